// Round 9
// baseline (2065.264 us; speedup 1.0000x reference)
//
#include <hip/hip_runtime.h>
#include <hip/hip_cooperative_groups.h>
#include <math.h>

namespace cg = cooperative_groups;

#define N_NODES 50000
#define N_EDGES 800000
#define IN_DIM 256
#define HID 128
#define NTILE 196            // ceil(N_NODES/256)
#define NTHR 1024

typedef unsigned short u16;
typedef u16 u16x8 __attribute__((ext_vector_type(8)));
typedef u16 u16x2 __attribute__((ext_vector_type(2)));
typedef __bf16 bf16x8 __attribute__((ext_vector_type(8)));
typedef float f32x4 __attribute__((ext_vector_type(4)));

#define AS1 __attribute__((address_space(1)))
#define AS3 __attribute__((address_space(3)))

union F8 { u16x8 u; bf16x8 h; };

__device__ __forceinline__ u16 f2b(float f) {
    unsigned u = __builtin_bit_cast(unsigned, f);
    u = (u + 0x7FFFu + ((u >> 16) & 1u)) >> 16;   // RNE
    return (u16)u;
}
__device__ __forceinline__ float b2f(u16 h) {
    unsigned u = ((unsigned)h) << 16;
    return __builtin_bit_cast(float, u);
}

// ---------------------------------------------------------------------------
template<int A_F32> struct ARaw;
template<> struct ARaw<0> { u16x8 v; };
template<> struct ARaw<1> { float4 f0, f1; };

template<int A_F32>
__device__ __forceinline__ ARaw<A_F32> load_raw(const void* base, size_t row, int P, int koff);
template<>
__device__ __forceinline__ ARaw<0> load_raw<0>(const void* base, size_t row, int P, int koff) {
    ARaw<0> r;
    r.v = *reinterpret_cast<const u16x8*>((const u16*)base + row * P + koff);
    return r;
}
template<>
__device__ __forceinline__ ARaw<1> load_raw<1>(const void* base, size_t row, int P, int koff) {
    ARaw<1> r;
    const float* p = (const float*)base + row * P + koff;
    r.f0 = *reinterpret_cast<const float4*>(p);
    r.f1 = *reinterpret_cast<const float4*>(p + 4);
    return r;
}

template<int A_F32>
__device__ __forceinline__ F8 to_frag(const ARaw<A_F32>& r);
template<>
__device__ __forceinline__ F8 to_frag<0>(const ARaw<0>& r) { F8 f; f.u = r.v; return f; }
template<>
__device__ __forceinline__ F8 to_frag<1>(const ARaw<1>& r) {
    F8 f;
    f.h[0] = (__bf16)r.f0.x; f.h[1] = (__bf16)r.f0.y;
    f.h[2] = (__bf16)r.f0.z; f.h[3] = (__bf16)r.f0.w;
    f.h[4] = (__bf16)r.f1.x; f.h[5] = (__bf16)r.f1.y;
    f.h[6] = (__bf16)r.f1.z; f.h[7] = (__bf16)r.f1.w;
    return f;
}

// ---------------------------------------------------------------------------
struct Params {
    const float* x; const int* src; const int* dst;
    const float* W_in; const float* b_in;
    const float* g1; const float* be1;
    const float* Wl1; const float* bl1; const float* Wr1;
    const float* Wl2; const float* bl2; const float* Wr2;
    const float* Wskip; const float* bskip;
    const float* g2; const float* be2;
    float* out;
    u16 *AGG, *H, *H1;
    float* stats;           // [512]: bn1 sum/sumsq ; +256: bn2
    int* icnt; int* row_ptr; int* fillrp; int* bsum; int* col_idx;
    float* bnc;             // scale1[128] shift1[128] scale2[128] shift2[128]
    u16 *WfA, *WfB, *WfC;
};

// ---------------------------------------------------------------------------
// weight -> fragment-ordered bf16 (one 512-thread chunk per K-32 slice)
// ---------------------------------------------------------------------------
__device__ __forceinline__ void conv_seg(int tid, const float* s0, const float* s1,
                                         const float* s2, int rows_each, u16* dst)
{
    int c   = tid >> 9;
    int j   = (tid >> 6) & 7;
    int l   = tid & 63;
    int l15 = l & 15, lg = l >> 4;
    int srow0 = c * 32;
    int si    = srow0 / rows_each;
    const float* S = (si == 0) ? s0 : (si == 1) ? s1 : s2;
    int rbase = srow0 - si * rows_each + lg * 8;
    int col   = 16 * j + l15;
    u16x8 o;
#pragma unroll
    for (int i = 0; i < 8; ++i) o[i] = f2b(S[(size_t)(rbase + i) * HID + col]);
    reinterpret_cast<u16x8*>(dst)[tid] = o;
}

// ---------------------------------------------------------------------------
// GEMM phase: C[M,128] = act(A @ Wf + bias0 (+bias1)), K = NC*32.
// 16 waves/block, BM=256, one 16-row M-frag per wave; tile-strided over 196.
// ---------------------------------------------------------------------------
template<int LEAKY, int STATS, int OUT_BF16, int A_F32, int NC, int C0, int C1>
__device__ void gemm_phase(const void* A0, const void* A1, const void* A2,
                           const u16* __restrict__ Wf,
                           const float* __restrict__ bias0, const float* __restrict__ bias1,
                           void* __restrict__ Cout, float* __restrict__ stats,
                           u16* Bs, float* sred)
{
    const int t   = threadIdx.x;
    const int w   = t >> 6;
    const int l   = t & 63;
    const int l15 = l & 15;
    const int lg  = l >> 4;
    const int ko  = lg * 8;

    // stage B panel (same for every tile) -> LDS
    for (int idx = t; idx < NC * 512; idx += NTHR)
        __builtin_amdgcn_global_load_lds(
            (const AS1 void*)(Wf + (size_t)idx * 8),
            (AS3 void*)(Bs + (size_t)idx * 8), 16, 0, 0);
    __syncthreads();

    float bias_j[8];
#pragma unroll
    for (int j = 0; j < 8; ++j) {
        float bb = bias0[16 * j + l15];
        if (bias1) bb += bias1[16 * j + l15];
        bias_j[j] = bb;
    }

    float csum[8], csq[8];
#pragma unroll
    for (int j = 0; j < 8; ++j) { csum[j] = 0.f; csq[j] = 0.f; }

    for (int tile = blockIdx.x; tile < NTILE; tile += gridDim.x) {
        const int rb = tile * 256 + w * 16;
        int r0 = rb + l15;
        size_t r0c = (size_t)(r0 < N_NODES ? r0 : N_NODES - 1);

        auto loadA = [&](int c) -> ARaw<A_F32> {
            if (A_F32) {
                return load_raw<A_F32>(A0, r0c, IN_DIM, c * 32 + ko);
            } else {
                const void* S = (c < C0) ? A0 : (c < C1) ? A1 : A2;
                int base      = (c < C0) ? 0  : (c < C1) ? C0 : C1;
                return load_raw<A_F32>(S, r0c, HID, (c - base) * 32 + ko);
            }
        };

        f32x4 acc[8];
#pragma unroll
        for (int j = 0; j < 8; ++j) acc[j] = 0.0f;

        ARaw<A_F32> ac = loadA(0), an;
#pragma unroll
        for (int c = 0; c < NC; ++c) {
            if (c + 1 < NC) an = loadA(c + 1);
            F8 fa = to_frag<A_F32>(ac);
#pragma unroll
            for (int j = 0; j < 8; ++j) {
                F8 b;
                b.u = *reinterpret_cast<const u16x8*>(Bs + (size_t)((c * 8 + j) * 64 + l) * 8);
                acc[j] = __builtin_amdgcn_mfma_f32_16x16x32_bf16(fa.h, b.h, acc[j], 0, 0, 0);
            }
            ac = an;
        }

        int rbase = rb + lg * 4;
#pragma unroll
        for (int r = 0; r < 4; ++r) {
            int row = rbase + r;
            bool ok = row < N_NODES;
#pragma unroll
            for (int j = 0; j < 8; ++j) {
                float y = acc[j][r] + bias_j[j];
                if (LEAKY) y = (y >= 0.f) ? y : 0.2f * y;
                if (ok) {
                    if (OUT_BF16)
                        ((u16*)Cout)[(size_t)row * HID + 16 * j + l15] = f2b(y);
                    else
                        ((float*)Cout)[(size_t)row * HID + 16 * j + l15] = y;
                    if (STATS) { csum[j] += y; csq[j] += y * y; }
                }
            }
        }
    }

    if (STATS) {
        if (t < 256) sred[t] = 0.f;
        __syncthreads();
#pragma unroll
        for (int j = 0; j < 8; ++j) {
            float s = csum[j];
            float q = csq[j];
            s += __shfl_xor(s, 16); s += __shfl_xor(s, 32);
            q += __shfl_xor(q, 16); q += __shfl_xor(q, 32);
            if (lg == 0) {
                atomicAdd(&sred[16 * j + l15], s);
                atomicAdd(&sred[128 + 16 * j + l15], q);
            }
        }
        __syncthreads();
        if (t < 256) atomicAdd(&stats[t], sred[t]);
    }
}

// ---------------------------------------------------------------------------
// SpMM mean phase: one wave per node, ushort2 per lane, 16 waves/block.
// ---------------------------------------------------------------------------
__device__ void spmm_phase(const int* __restrict__ row_ptr, const int* __restrict__ col_idx,
                           const u16* __restrict__ Hin, u16* __restrict__ Aout)
{
    int w = threadIdx.x >> 6;
    int lane = threadIdx.x & 63;
    for (int node = blockIdx.x * 16 + w; node < N_NODES; node += gridDim.x * 16) {
        int beg = row_ptr[node];
        int end = row_ptr[node + 1];
        float sx = 0.f, sy = 0.f;
        int e = beg;
        for (; e + 4 <= end; e += 4) {
            int c0 = col_idx[e], c1 = col_idx[e + 1], c2 = col_idx[e + 2], c3 = col_idx[e + 3];
            u16x2 v0 = *reinterpret_cast<const u16x2*>(Hin + (size_t)c0 * HID + lane * 2);
            u16x2 v1 = *reinterpret_cast<const u16x2*>(Hin + (size_t)c1 * HID + lane * 2);
            u16x2 v2 = *reinterpret_cast<const u16x2*>(Hin + (size_t)c2 * HID + lane * 2);
            u16x2 v3 = *reinterpret_cast<const u16x2*>(Hin + (size_t)c3 * HID + lane * 2);
            sx += (b2f(v0[0]) + b2f(v1[0])) + (b2f(v2[0]) + b2f(v3[0]));
            sy += (b2f(v0[1]) + b2f(v1[1])) + (b2f(v2[1]) + b2f(v3[1]));
        }
        for (; e < end; ++e) {
            int c = col_idx[e];
            u16x2 v = *reinterpret_cast<const u16x2*>(Hin + (size_t)c * HID + lane * 2);
            sx += b2f(v[0]); sy += b2f(v[1]);
        }
        float inv = 1.f / fmaxf((float)(end - beg), 1.f);
        u16x2 r; r[0] = f2b(sx * inv); r[1] = f2b(sy * inv);
        *reinterpret_cast<u16x2*>(Aout + (size_t)node * HID + lane * 2) = r;
    }
}

__device__ __forceinline__ void bn_param_calc(const float* st, const float* gamma,
                                              const float* beta, float* scale,
                                              float* shift, int j)
{
    float mean = st[j] * (1.f / N_NODES);
    float var  = st[128 + j] * (1.f / N_NODES) - mean * mean;
    var = fmaxf(var, 0.f);
    float sc = gamma[j] / sqrtf(var + 1e-5f);
    scale[j] = sc;
    shift[j] = beta[j] - mean * sc;
}

// ---------------------------------------------------------------------------
// The whole pipeline as ONE cooperative kernel (kills ~15 launch gaps).
// ---------------------------------------------------------------------------
__global__ __launch_bounds__(NTHR, 4) void mega(Params p)
{
    __shared__ u16 Bs[12 * 4096];     // 96 KB: B panels / scan scratch
    __shared__ float sred[256];

    cg::grid_group gg = cg::this_grid();
    const int t = threadIdx.x;
    const int gtid = blockIdx.x * NTHR + t;
    const int gstride = gridDim.x * NTHR;

    // P0a: zero stats + icnt
    for (int i = gtid; i < 512 + N_NODES; i += gstride) {
        if (i < 512) p.stats[i] = 0.f;
        else         p.icnt[i - 512] = 0;
    }
    __threadfence();
    gg.sync();

    // P0b: weight conversion (all unscaled) + edge count
    if (gtid < 4096)        conv_seg(gtid,        p.W_in, nullptr, nullptr, 256, p.WfA);
    else if (gtid < 8192)   conv_seg(gtid - 4096, p.Wl1,  p.Wr1,   nullptr, 128, p.WfB);
    else if (gtid < 14336)  conv_seg(gtid - 8192, p.Wl2,  p.Wskip, p.Wr2,   128, p.WfC);
    for (int e = gtid; e < N_EDGES; e += gstride)
        atomicAdd(&p.icnt[p.dst[e]], 1);
    __threadfence();
    gg.sync();

    // P1: per-256 block scan of icnt -> row_ptr (exclusive), bsum
    {
        int* shs = (int*)Bs;
        for (int vb = blockIdx.x; vb < NTILE; vb += gridDim.x) {
            int i = vb * 256 + (t & 255);
            int v = (t < 256 && i < N_NODES) ? p.icnt[i] : 0;
            if (t < 256) shs[t] = v;
            __syncthreads();
            for (int off = 1; off < 256; off <<= 1) {
                int x = (t < 256 && t >= off) ? shs[t - off] : 0;
                __syncthreads();
                if (t < 256) shs[t] += x;
                __syncthreads();
            }
            if (t < 256 && i < N_NODES) p.row_ptr[i] = shs[t] - v;
            if (t == 255) p.bsum[vb] = shs[255];
            __syncthreads();
        }
    }
    __threadfence();
    gg.sync();

    // P2: scan bsum (block 0)
    if (blockIdx.x == 0) {
        int* shs = (int*)Bs;
        int v = (t < NTILE) ? p.bsum[t] : 0;
        if (t < 256) shs[t] = v;
        __syncthreads();
        for (int off = 1; off < 256; off <<= 1) {
            int x = (t < 256 && t >= off) ? shs[t - off] : 0;
            __syncthreads();
            if (t < 256) shs[t] += x;
            __syncthreads();
        }
        if (t < NTILE) p.bsum[t] = shs[t] - v;
    }
    __threadfence();
    gg.sync();

    // P3: add block offsets; init fillrp
    for (int i = gtid; i < N_NODES; i += gstride) {
        int v = p.row_ptr[i] + p.bsum[i >> 8];
        p.row_ptr[i] = v;
        p.fillrp[i]  = v;
    }
    if (gtid == 0) p.row_ptr[N_NODES] = N_EDGES;
    __threadfence();
    gg.sync();

    // P4: XCD-partitioned CSR fill (range fixed per physical block)
    {
        const int range = blockIdx.x & 7;
        const int lo = range * 6250, hi = lo + 6250;
        for (int vb = blockIdx.x; vb < NTILE * 8; vb += gridDim.x) {
            int base = (vb >> 3) * 4096;
#pragma unroll
            for (int k = 0; k < 4; ++k) {
                int e = base + k * 1024 + t;
                if (e < N_EDGES) {
                    int d = p.dst[e];
                    if (d >= lo && d < hi) {
                        int pos = atomicAdd(&p.fillrp[d], 1);
                        p.col_idx[pos] = p.src[e];
                    }
                }
            }
        }
    }
    __threadfence();
    gg.sync();

    // P5: gemm0  H = leaky(x @ WfA + b_in), stats1
    gemm_phase<1, 1, 1, 1, 8, 8, 8>(p.x, nullptr, nullptr, p.WfA, p.b_in, nullptr,
                                    p.H, p.stats, Bs, sred);
    __threadfence();
    gg.sync();

    // P6: bn1 params
    if (blockIdx.x == 0 && t < 128)
        bn_param_calc(p.stats, p.g1, p.be1, p.bnc, p.bnc + 128, t);
    __threadfence();
    gg.sync();

    // P7: apply BN1 in place on H
    for (int i = gtid; i < N_NODES * 16; i += gstride) {
        int row = i >> 4, g = i & 15;
        u16* q = p.H + (size_t)row * HID + g * 8;
        u16x8 v = *reinterpret_cast<u16x8*>(q);
        u16x8 o;
#pragma unroll
        for (int e = 0; e < 8; ++e)
            o[e] = f2b(b2f(v[e]) * p.bnc[g * 8 + e] + p.bnc[128 + g * 8 + e]);
        *reinterpret_cast<u16x8*>(q) = o;
    }
    __threadfence();
    gg.sync();

    // P8: spmm1  AGG = mean(H)
    spmm_phase(p.row_ptr, p.col_idx, p.H, p.AGG);
    __threadfence();
    gg.sync();

    // P9: gemm1  H1 = leaky([AGG|H] @ WfB + bl1)
    gemm_phase<1, 0, 1, 0, 8, 4, 8>(p.AGG, p.H, nullptr, p.WfB, p.bl1, nullptr,
                                    p.H1, nullptr, Bs, sred);
    __threadfence();
    gg.sync();

    // P10: spmm2  AGG = mean(H1)
    spmm_phase(p.row_ptr, p.col_idx, p.H1, p.AGG);
    __threadfence();
    gg.sync();

    // P11: gemm2  out = [AGG|H|H1] @ WfC + bl2 + bskip, stats2 (fp32)
    gemm_phase<0, 1, 0, 0, 12, 4, 8>(p.AGG, p.H, p.H1, p.WfC, p.bl2, p.bskip,
                                     p.out, p.stats + 256, Bs, sred);
    __threadfence();
    gg.sync();

    // P12: bn2 params
    if (blockIdx.x == 0 && t < 128)
        bn_param_calc(p.stats + 256, p.g2, p.be2, p.bnc + 256, p.bnc + 384, t);
    __threadfence();
    gg.sync();

    // P13: BN2 + L2 row normalize, in place on out
    {
        int w = t >> 6, lane = t & 63;
        for (int node = blockIdx.x * 16 + w; node < N_NODES; node += gridDim.x * 16) {
            float2 v = *reinterpret_cast<const float2*>(p.out + (size_t)node * HID + lane * 2);
            float y0 = v.x * p.bnc[256 + lane * 2]     + p.bnc[384 + lane * 2];
            float y1 = v.y * p.bnc[256 + lane * 2 + 1] + p.bnc[384 + lane * 2 + 1];
            float ss = y0 * y0 + y1 * y1;
#pragma unroll
            for (int m = 1; m < 64; m <<= 1) ss += __shfl_xor(ss, m);
            float inv = 1.f / fmaxf(sqrtf(ss), 1e-12f);
            float2 r = {y0 * inv, y1 * inv};
            *reinterpret_cast<float2*>(p.out + (size_t)node * HID + lane * 2) = r;
        }
    }
}

// ---------------------------------------------------------------------------
extern "C" void kernel_launch(void* const* d_in, const int* in_sizes, int n_in,
                              void* d_out, int out_size, void* d_ws, size_t ws_size,
                              hipStream_t stream)
{
    Params p;
    p.x     = (const float*)d_in[0];
    const int* ei = (const int*)d_in[1];
    p.src   = ei;
    p.dst   = ei + N_EDGES;
    p.W_in  = (const float*)d_in[2];
    p.b_in  = (const float*)d_in[3];
    p.g1    = (const float*)d_in[4];
    p.be1   = (const float*)d_in[5];
    p.Wl1   = (const float*)d_in[6];
    p.bl1   = (const float*)d_in[7];
    p.Wr1   = (const float*)d_in[8];
    p.Wl2   = (const float*)d_in[9];
    p.bl2   = (const float*)d_in[10];
    p.Wr2   = (const float*)d_in[11];
    p.Wskip = (const float*)d_in[12];
    p.bskip = (const float*)d_in[13];
    p.g2    = (const float*)d_in[14];
    p.be2   = (const float*)d_in[15];
    p.out   = (float*)d_out;

    const size_t NB16 = (size_t)N_NODES * HID;
    char* ws = (char*)d_ws;
    p.AGG = (u16*)ws;
    p.H   = p.AGG + NB16;
    p.H1  = p.H + NB16;
    char* zz = ws + 3 * NB16 * 2;
    p.stats   = (float*)zz;                          // 512 f
    p.icnt    = (int*)(zz + 2048);                   // N
    p.row_ptr = (int*)(zz + 2048 + 200000);          // N+1
    p.fillrp  = (int*)(zz + 2048 + 400064);          // N
    p.bsum    = (int*)(zz + 2048 + 600064);          // 256
    p.col_idx = (int*)(zz + 2048 + 601088);          // E
    p.bnc     = (float*)(zz + 2048 + 601088 + (size_t)N_EDGES * 4);
    p.WfA     = (u16*)((char*)p.bnc + 2048);
    p.WfB     = p.WfA + 8 * 4096;
    p.WfC     = p.WfB + 8 * 4096;

    int maxb = 1;
    (void)hipOccupancyMaxActiveBlocksPerMultiprocessor(&maxb, mega, NTHR, 0);
    if (maxb < 1) maxb = 1;
    int grid = maxb * 256;
    if (grid > 256) grid = 256;
    grid &= ~7;                      // edge_fill needs grid % 8 == 0
    if (grid < 8) grid = 8;

    void* args[] = { &p };
    hipLaunchCooperativeKernel(mega, dim3(grid), dim3(NTHR), args, 0, stream);
}

// Round 10
// 293.996 us; speedup vs baseline: 7.0248x; 7.0248x over previous
//
#include <hip/hip_runtime.h>
#include <math.h>

#define N_NODES 50000
#define N_EDGES 800000
#define IN_DIM 256
#define HID 128
#define NTILE 196   // ceil(N_NODES/256)

typedef unsigned short u16;
typedef u16 u16x8 __attribute__((ext_vector_type(8)));
typedef u16 u16x2 __attribute__((ext_vector_type(2)));
typedef __bf16 bf16x8 __attribute__((ext_vector_type(8)));
typedef float f32x4 __attribute__((ext_vector_type(4)));

#define AS1 __attribute__((address_space(1)))
#define AS3 __attribute__((address_space(3)))

union F8 { u16x8 u; bf16x8 h; };

__device__ __forceinline__ u16 f2b(float f) {
    unsigned u = __builtin_bit_cast(unsigned, f);
    u = (u + 0x7FFFu + ((u >> 16) & 1u)) >> 16;   // RNE
    return (u16)u;
}
__device__ __forceinline__ float b2f(u16 h) {
    unsigned u = ((unsigned)h) << 16;
    return __builtin_bit_cast(float, u);
}

// ---------------------------------------------------------------------------
// weight -> fragment-ordered bf16 segment (tid in units of 64-lane frag rows)
// ---------------------------------------------------------------------------
__device__ __forceinline__ void conv_seg(int tid, const float* s0, const float* s1,
                                         const float* s2, int rows_each, u16* dst)
{
    int c   = tid >> 9;
    int j   = (tid >> 6) & 7;
    int l   = tid & 63;
    int l15 = l & 15, lg = l >> 4;
    int srow0 = c * 32;
    int si    = srow0 / rows_each;
    const float* S = (si == 0) ? s0 : (si == 1) ? s1 : s2;
    int rbase = srow0 - si * rows_each + lg * 8;
    int col   = 16 * j + l15;
    u16x8 o;
#pragma unroll
    for (int i = 0; i < 8; ++i) o[i] = f2b(S[(size_t)(rbase + i) * HID + col]);
    reinterpret_cast<u16x8*>(dst)[tid] = o;
}

// blocks 0..55: weight conversion (WfA 16, WfB 16, WfC 24); rest: edge count
__global__ __launch_bounds__(256) void convcnt_k(
    const float* W_in, const float* Wl1, const float* Wr1,
    const float* Wl2, const float* Wskip, const float* Wr2,
    u16* WfA, u16* WfB, u16* WfC,
    const int* __restrict__ dst, int* __restrict__ icnt)
{
    int b = blockIdx.x;
    if (b < 56) {
        int tid = b * 256 + threadIdx.x;
        if (tid < 4096)      conv_seg(tid,        W_in, nullptr, nullptr, 256, WfA);
        else if (tid < 8192) conv_seg(tid - 4096, Wl1,  Wr1,     nullptr, 128, WfB);
        else                 conv_seg(tid - 8192, Wl2,  Wskip,   Wr2,     128, WfC);
    } else {
        int e = (b - 56) * 256 + threadIdx.x;
        if (e < N_EDGES) atomicAdd(&icnt[dst[e]], 1);
    }
}

// ---------------------------------------------------------------------------
// CSR build (unchanged from R8 — known good)
// ---------------------------------------------------------------------------
__global__ __launch_bounds__(256) void scan_block(const int* __restrict__ cnt,
                                                  int* __restrict__ excl,
                                                  int* __restrict__ bsum, int n)
{
    __shared__ int sh[256];
    int t = threadIdx.x;
    int i = blockIdx.x * 256 + t;
    int v = (i < n) ? cnt[i] : 0;
    sh[t] = v;
    __syncthreads();
#pragma unroll
    for (int off = 1; off < 256; off <<= 1) {
        int x = (t >= off) ? sh[t - off] : 0;
        __syncthreads();
        sh[t] += x;
        __syncthreads();
    }
    if (i < n) excl[i] = sh[t] - v;
    if (t == 255) bsum[blockIdx.x] = sh[255];
}

__global__ __launch_bounds__(256) void scan_bsum(int* __restrict__ bsum, int nb)
{
    __shared__ int sh[256];
    int t = threadIdx.x;
    int v = (t < nb) ? bsum[t] : 0;
    sh[t] = v;
    __syncthreads();
#pragma unroll
    for (int off = 1; off < 256; off <<= 1) {
        int x = (t >= off) ? sh[t - off] : 0;
        __syncthreads();
        sh[t] += x;
        __syncthreads();
    }
    if (t < nb) bsum[t] = sh[t] - v;   // exclusive
}

__global__ __launch_bounds__(256) void scan_add(int* __restrict__ row_ptr,
                                                int* __restrict__ fillrp,
                                                const int* __restrict__ bsum, int n)
{
    int i = blockIdx.x * 256 + threadIdx.x;
    if (i < n) {
        int v = row_ptr[i] + bsum[i >> 8];
        row_ptr[i] = v;
        fillrp[i]  = v;
    }
    if (i == 0) row_ptr[n] = N_EDGES;
}

#define FILL_EPB 4096
__global__ __launch_bounds__(256) void edge_fill_part(const int* __restrict__ src,
                                                      const int* __restrict__ dst,
                                                      int* __restrict__ fillrp,
                                                      int* __restrict__ col_idx)
{
    const int range = blockIdx.x & 7;
    const int base  = (blockIdx.x >> 3) * FILL_EPB;
    const int lo = range * 6250, hi = lo + 6250;
#pragma unroll
    for (int k = 0; k < FILL_EPB / 256; ++k) {
        int e = base + k * 256 + threadIdx.x;
        if (e < N_EDGES) {
            int d = dst[e];
            if (d >= lo && d < hi) {
                int pos = atomicAdd(&fillrp[d], 1);
                col_idx[pos] = src[e];
            }
        }
    }
}

// ---------------------------------------------------------------------------
// gemm0: H = leaky(x(fp32) @ WfA + b_in), stats1. 512 thr, BM=256 (2 Mfrag/wave).
// ---------------------------------------------------------------------------
__global__ __launch_bounds__(512, 2) void gemm0_k(
    const float* __restrict__ x, const u16* __restrict__ Wf,
    const float* __restrict__ bias, u16* __restrict__ H,
    float* __restrict__ stats)
{
    __shared__ u16 Bs[8 * 4096];
    __shared__ float sred[256];
    const int t = threadIdx.x, w = t >> 6, l = t & 63, l15 = l & 15, lg = l >> 4;
    const int rb = blockIdx.x * 256 + w * 32;
    const int r0 = rb + l15, r1 = r0 + 16;
    const size_t r0c = (size_t)(r0 < N_NODES ? r0 : N_NODES - 1);
    const size_t r1c = (size_t)(r1 < N_NODES ? r1 : N_NODES - 1);
    const int ko = lg * 8;

#pragma unroll
    for (int i = 0; i < 8; ++i) {
        int idx = i * 512 + t;
        __builtin_amdgcn_global_load_lds((const AS1 void*)(Wf + (size_t)idx * 8),
                                         (AS3 void*)(Bs + (size_t)idx * 8), 16, 0, 0);
    }
    __syncthreads();

    f32x4 acc[2][8];
#pragma unroll
    for (int m = 0; m < 2; ++m)
#pragma unroll
        for (int j = 0; j < 8; ++j) acc[m][j] = 0.0f;

#pragma unroll
    for (int c = 0; c < 8; ++c) {
        F8 fa0, fa1;
        {
            const float* p = x + r0c * IN_DIM + c * 32 + ko;
            float4 f0 = *reinterpret_cast<const float4*>(p);
            float4 f1 = *reinterpret_cast<const float4*>(p + 4);
            fa0.h[0] = (__bf16)f0.x; fa0.h[1] = (__bf16)f0.y;
            fa0.h[2] = (__bf16)f0.z; fa0.h[3] = (__bf16)f0.w;
            fa0.h[4] = (__bf16)f1.x; fa0.h[5] = (__bf16)f1.y;
            fa0.h[6] = (__bf16)f1.z; fa0.h[7] = (__bf16)f1.w;
        }
        {
            const float* p = x + r1c * IN_DIM + c * 32 + ko;
            float4 f0 = *reinterpret_cast<const float4*>(p);
            float4 f1 = *reinterpret_cast<const float4*>(p + 4);
            fa1.h[0] = (__bf16)f0.x; fa1.h[1] = (__bf16)f0.y;
            fa1.h[2] = (__bf16)f0.z; fa1.h[3] = (__bf16)f0.w;
            fa1.h[4] = (__bf16)f1.x; fa1.h[5] = (__bf16)f1.y;
            fa1.h[6] = (__bf16)f1.z; fa1.h[7] = (__bf16)f1.w;
        }
#pragma unroll
        for (int j = 0; j < 8; ++j) {
            F8 b;
            b.u = *reinterpret_cast<const u16x8*>(Bs + (size_t)((c * 8 + j) * 64 + l) * 8);
            acc[0][j] = __builtin_amdgcn_mfma_f32_16x16x32_bf16(fa0.h, b.h, acc[0][j], 0, 0, 0);
            acc[1][j] = __builtin_amdgcn_mfma_f32_16x16x32_bf16(fa1.h, b.h, acc[1][j], 0, 0, 0);
        }
    }

    float bias_j[8];
#pragma unroll
    for (int j = 0; j < 8; ++j) bias_j[j] = bias[16 * j + l15];

    float csum[8], csq[8];
#pragma unroll
    for (int j = 0; j < 8; ++j) { csum[j] = 0.f; csq[j] = 0.f; }

#pragma unroll
    for (int m = 0; m < 2; ++m) {
        int rbase = rb + m * 16 + lg * 4;
#pragma unroll
        for (int r = 0; r < 4; ++r) {
            int row = rbase + r;
            bool ok = row < N_NODES;
#pragma unroll
            for (int j = 0; j < 8; ++j) {
                float y = acc[m][j][r] + bias_j[j];
                y = (y >= 0.f) ? y : 0.2f * y;
                if (ok) {
                    H[(size_t)row * HID + 16 * j + l15] = f2b(y);
                    csum[j] += y; csq[j] += y * y;
                }
            }
        }
    }

    if (t < 256) sred[t] = 0.f;
    __syncthreads();
#pragma unroll
    for (int j = 0; j < 8; ++j) {
        float s = csum[j];
        float q = csq[j];
        s += __shfl_xor(s, 16); s += __shfl_xor(s, 32);
        q += __shfl_xor(q, 16); q += __shfl_xor(q, 32);
        if (lg == 0) {
            atomicAdd(&sred[16 * j + l15], s);
            atomicAdd(&sred[128 + 16 * j + l15], q);
        }
    }
    __syncthreads();
    if (t < 256) atomicAdd(&stats[t], sred[t]);
}

// ---------------------------------------------------------------------------
// bn_apply: H = bn1(H) in place. Params computed per-block (redundant, cheap).
// ---------------------------------------------------------------------------
__global__ __launch_bounds__(256) void bn_apply_k(
    u16* __restrict__ H, const float* __restrict__ stats,
    const float* __restrict__ g1, const float* __restrict__ be1)
{
    __shared__ float sc[128], sh[128];
    int t = threadIdx.x;
    if (t < 128) {
        float mean = stats[t] * (1.f / N_NODES);
        float var  = fmaxf(stats[128 + t] * (1.f / N_NODES) - mean * mean, 0.f);
        float s = g1[t] / sqrtf(var + 1e-5f);
        sc[t] = s; sh[t] = be1[t] - mean * s;
    }
    __syncthreads();
    int idx = blockIdx.x * 256 + t;
    if (idx >= N_NODES * 16) return;
    int g = (idx & 15) * 8;
    u16x8 v = *reinterpret_cast<u16x8*>(H + (size_t)idx * 8);
    u16x8 o;
#pragma unroll
    for (int e = 0; e < 8; ++e) o[e] = f2b(b2f(v[e]) * sc[g + e] + sh[g + e]);
    *reinterpret_cast<u16x8*>(H + (size_t)idx * 8) = o;
}

// ---------------------------------------------------------------------------
// Fused SAGE: per block (256 output rows, 16 waves x 16 rows):
//   wave gathers mean of Gsrc over its 16 nodes -> private swizzled LDS tile
//   (chunks 0-3 A-operand), chunks 4-7 = Aop1 rows, chunks 8-11 = Aop2 (TWO_STAGE).
//   C = act([AGG|Aop1(|Aop2)] @ Wf + bias0(+bias1)).
// The AGG rows a block needs are exactly the nodes it owns -> fusion is local.
// ---------------------------------------------------------------------------
template<int NC, int TWO_STAGE, int LEAKY, int STATS, int OUT_BF16>
__global__ __launch_bounds__(1024, 4) void sage_k(
    const int* __restrict__ row_ptr, const int* __restrict__ col_idx,
    const u16* __restrict__ Gsrc, const u16* __restrict__ Aop1,
    const u16* __restrict__ Aop2, const u16* __restrict__ Wf,
    const float* __restrict__ bias0, const float* __restrict__ bias1,
    void* __restrict__ Cout, float* __restrict__ stats)
{
    __shared__ u16 Bs[8 * 4096];     // B chunks 0-7
    __shared__ u16 At[16 * 2048];    // per-wave AGG tiles; reused for B chunks 8-11
    __shared__ float sred[256];

    const int t = threadIdx.x, w = t >> 6, l = t & 63, l15 = l & 15, lg = l >> 4;
    const int rb = blockIdx.x * 256 + w * 16;
    const int r0 = rb + l15;
    const size_t r0c = (size_t)(r0 < N_NODES ? r0 : N_NODES - 1);
    const int ko = lg * 8;

    // stage B chunks 0..7 (async, overlaps gather)
    for (int idx = t; idx < 8 * 512; idx += 1024)
        __builtin_amdgcn_global_load_lds((const AS1 void*)(Wf + (size_t)idx * 8),
                                         (AS3 void*)(Bs + (size_t)idx * 8), 16, 0, 0);

    // prefetch global A fragments (overlap with gather)
    u16x8 av[4];
#pragma unroll
    for (int c = 0; c < 4; ++c)
        av[c] = *reinterpret_cast<const u16x8*>(Aop1 + r0c * HID + c * 32 + ko);
    u16x8 bv[4];
    if (TWO_STAGE) {
#pragma unroll
        for (int c = 0; c < 4; ++c)
            bv[c] = *reinterpret_cast<const u16x8*>(Aop2 + r0c * HID + c * 32 + ko);
    }

    // gather-mean: wave's 16 nodes -> swizzled LDS tile (wave-private)
    u16* wbase = At + w * 2048;
    for (int ni = 0; ni < 16; ++ni) {
        int node = rb + ni;
        float sx = 0.f, sy = 0.f, inv = 0.f;
        if (node < N_NODES) {
            int beg = row_ptr[node], end = row_ptr[node + 1];
            int e = beg;
            for (; e + 4 <= end; e += 4) {
                int c0 = col_idx[e], c1 = col_idx[e + 1], c2 = col_idx[e + 2], c3 = col_idx[e + 3];
                u16x2 v0 = *reinterpret_cast<const u16x2*>(Gsrc + (size_t)c0 * HID + l * 2);
                u16x2 v1 = *reinterpret_cast<const u16x2*>(Gsrc + (size_t)c1 * HID + l * 2);
                u16x2 v2 = *reinterpret_cast<const u16x2*>(Gsrc + (size_t)c2 * HID + l * 2);
                u16x2 v3 = *reinterpret_cast<const u16x2*>(Gsrc + (size_t)c3 * HID + l * 2);
                sx += (b2f(v0[0]) + b2f(v1[0])) + (b2f(v2[0]) + b2f(v3[0]));
                sy += (b2f(v0[1]) + b2f(v1[1])) + (b2f(v2[1]) + b2f(v3[1]));
            }
            for (; e < end; ++e) {
                int c = col_idx[e];
                u16x2 v = *reinterpret_cast<const u16x2*>(Gsrc + (size_t)c * HID + l * 2);
                sx += b2f(v[0]); sy += b2f(v[1]);
            }
            inv = 1.f / fmaxf((float)(end - beg), 1.f);
        }
        u16x2 rr; rr[0] = f2b(sx * inv); rr[1] = f2b(sy * inv);
        *reinterpret_cast<u16x2*>(wbase + ni * 128 + (((l >> 2) ^ ni) & 15) * 8 + (l & 3) * 2) = rr;
    }

    __syncthreads();   // B panel resident; At lgkm drained

    f32x4 acc[8];
#pragma unroll
    for (int j = 0; j < 8; ++j) acc[j] = 0.0f;

    // chunks 0-3: AGG from swizzled LDS tile
#pragma unroll
    for (int c = 0; c < 4; ++c) {
        F8 fa;
        fa.u = *reinterpret_cast<const u16x8*>(wbase + l15 * 128 + (((c * 4 + lg) ^ l15) & 15) * 8);
#pragma unroll
        for (int j = 0; j < 8; ++j) {
            F8 b;
            b.u = *reinterpret_cast<const u16x8*>(Bs + (size_t)((c * 8 + j) * 64 + l) * 8);
            acc[j] = __builtin_amdgcn_mfma_f32_16x16x32_bf16(fa.h, b.h, acc[j], 0, 0, 0);
        }
    }
    // chunks 4-7: Aop1 rows (prefetched)
#pragma unroll
    for (int c = 4; c < 8; ++c) {
        F8 fa; fa.u = av[c - 4];
#pragma unroll
        for (int j = 0; j < 8; ++j) {
            F8 b;
            b.u = *reinterpret_cast<const u16x8*>(Bs + (size_t)((c * 8 + j) * 64 + l) * 8);
            acc[j] = __builtin_amdgcn_mfma_f32_16x16x32_bf16(fa.h, b.h, acc[j], 0, 0, 0);
        }
    }
    if (TWO_STAGE) {
        __syncthreads();   // all waves done with At
        for (int idx = t; idx < 4 * 512; idx += 1024)
            __builtin_amdgcn_global_load_lds((const AS1 void*)(Wf + (size_t)(4096 + idx) * 8),
                                             (AS3 void*)(At + (size_t)idx * 8), 16, 0, 0);
        __syncthreads();   // B chunks 8-11 resident in At
#pragma unroll
        for (int c = 8; c < 12; ++c) {
            F8 fa; fa.u = bv[c - 8];
#pragma unroll
            for (int j = 0; j < 8; ++j) {
                F8 b;
                b.u = *reinterpret_cast<const u16x8*>(At + (size_t)(((c - 8) * 8 + j) * 64 + l) * 8);
                acc[j] = __builtin_amdgcn_mfma_f32_16x16x32_bf16(fa.h, b.h, acc[j], 0, 0, 0);
            }
        }
    }

    // epilogue
    float bias_j[8];
#pragma unroll
    for (int j = 0; j < 8; ++j) {
        float bb = bias0[16 * j + l15];
        if (bias1) bb += bias1[16 * j + l15];
        bias_j[j] = bb;
    }

    float csum[8], csq[8];
#pragma unroll
    for (int j = 0; j < 8; ++j) { csum[j] = 0.f; csq[j] = 0.f; }

    int rbase = rb + lg * 4;
#pragma unroll
    for (int r = 0; r < 4; ++r) {
        int row = rbase + r;
        bool ok = row < N_NODES;
#pragma unroll
        for (int j = 0; j < 8; ++j) {
            float y = acc[j][r] + bias_j[j];
            if (LEAKY) y = (y >= 0.f) ? y : 0.2f * y;
            if (ok) {
                if (OUT_BF16)
                    ((u16*)Cout)[(size_t)row * HID + 16 * j + l15] = f2b(y);
                else
                    ((float*)Cout)[(size_t)row * HID + 16 * j + l15] = y;
                if (STATS) { csum[j] += y; csq[j] += y * y; }
            }
        }
    }

    if (STATS) {
        __syncthreads();
        if (t < 256) sred[t] = 0.f;
        __syncthreads();
#pragma unroll
        for (int j = 0; j < 8; ++j) {
            float s = csum[j];
            float q = csq[j];
            s += __shfl_xor(s, 16); s += __shfl_xor(s, 32);
            q += __shfl_xor(q, 16); q += __shfl_xor(q, 32);
            if (lg == 0) {
                atomicAdd(&sred[16 * j + l15], s);
                atomicAdd(&sred[128 + 16 * j + l15], q);
            }
        }
        __syncthreads();
        if (t < 256) atomicAdd(&stats[t], sred[t]);
    }
}

// ---------------------------------------------------------------------------
// rownorm: bn2 (params inline from stats2) + L2 row-normalize, in place.
// ---------------------------------------------------------------------------
__global__ __launch_bounds__(256) void rownorm_k(
    float* __restrict__ out, const float* __restrict__ stats2,
    const float* __restrict__ g2, const float* __restrict__ be2)
{
    __shared__ float sc[128], sh[128];
    int t = threadIdx.x;
    if (t < 128) {
        float mean = stats2[t] * (1.f / N_NODES);
        float var  = fmaxf(stats2[128 + t] * (1.f / N_NODES) - mean * mean, 0.f);
        float s = g2[t] / sqrtf(var + 1e-5f);
        sc[t] = s; sh[t] = be2[t] - mean * s;
    }
    __syncthreads();
    int row = blockIdx.x * 4 + (t >> 6);
    if (row >= N_NODES) return;
    int lane = t & 63;
    float2 v = *reinterpret_cast<const float2*>(&out[(size_t)row * HID + lane * 2]);
    float y0 = v.x * sc[lane * 2]     + sh[lane * 2];
    float y1 = v.y * sc[lane * 2 + 1] + sh[lane * 2 + 1];
    float ss = y0 * y0 + y1 * y1;
#pragma unroll
    for (int m = 1; m < 64; m <<= 1) ss += __shfl_xor(ss, m);
    float inv = 1.f / fmaxf(sqrtf(ss), 1e-12f);
    float2 r = {y0 * inv, y1 * inv};
    *reinterpret_cast<float2*>(&out[(size_t)row * HID + lane * 2]) = r;
}

// ---------------------------------------------------------------------------
extern "C" void kernel_launch(void* const* d_in, const int* in_sizes, int n_in,
                              void* d_out, int out_size, void* d_ws, size_t ws_size,
                              hipStream_t stream)
{
    const float* x     = (const float*)d_in[0];
    const int*   ei    = (const int*)d_in[1];
    const float* W_in  = (const float*)d_in[2];
    const float* b_in  = (const float*)d_in[3];
    const float* g1    = (const float*)d_in[4];
    const float* be1   = (const float*)d_in[5];
    const float* Wl1   = (const float*)d_in[6];
    const float* bl1   = (const float*)d_in[7];
    const float* Wr1   = (const float*)d_in[8];
    const float* Wl2   = (const float*)d_in[9];
    const float* bl2   = (const float*)d_in[10];
    const float* Wr2   = (const float*)d_in[11];
    const float* Wskip = (const float*)d_in[12];
    const float* bskip = (const float*)d_in[13];
    const float* g2    = (const float*)d_in[14];
    const float* be2   = (const float*)d_in[15];
    float* out = (float*)d_out;

    const size_t NB16 = (size_t)N_NODES * HID;
    char* ws = (char*)d_ws;
    u16* H  = (u16*)ws;                              // 12.8 MB
    u16* H1 = H + NB16;                              // 12.8 MB
    char* zz = ws + 2 * NB16 * 2;
    float* stats  = (float*)zz;                      // 512 f [zeroed]
    int* icnt     = (int*)(zz + 2048);               // N    [zeroed]
    size_t zsz    = 2048 + (size_t)N_NODES * 4;
    int* row_ptr  = (int*)(zz + 202048);             // N+1
    int* fillrp   = (int*)(zz + 402112);             // N
    int* bsum     = (int*)(zz + 602176);             // 256
    int* col_idx  = (int*)(zz + 603200);             // E
    u16* WfA      = (u16*)(zz + 603200 + (size_t)N_EDGES * 4);
    u16* WfB      = WfA + 8 * 4096;
    u16* WfC      = WfB + 8 * 4096;

    hipMemsetAsync(zz, 0, zsz, stream);

    const int* srcp = ei;
    const int* dstp = ei + N_EDGES;

    // weights + edge count (one kernel)
    convcnt_k<<<56 + (N_EDGES + 255) / 256, 256, 0, stream>>>(
        W_in, Wl1, Wr1, Wl2, Wskip, Wr2, WfA, WfB, WfC, dstp, icnt);

    // CSR
    scan_block<<<NTILE, 256, 0, stream>>>(icnt, row_ptr, bsum, N_NODES);
    scan_bsum<<<1, 256, 0, stream>>>(bsum, NTILE);
    scan_add<<<NTILE, 256, 0, stream>>>(row_ptr, fillrp, bsum, N_NODES);
    edge_fill_part<<<((N_EDGES + FILL_EPB - 1) / FILL_EPB) * 8, 256, 0, stream>>>(
        srcp, dstp, fillrp, col_idx);

    // layer 0 + BN1 (in place)
    gemm0_k<<<NTILE, 512, 0, stream>>>(x, WfA, b_in, H, stats);
    bn_apply_k<<<(N_NODES * 16 + 255) / 256, 256, 0, stream>>>(H, stats, g1, be1);

    // sage1: H1 = leaky([mean(H)|H] @ WfB + bl1)
    sage_k<8, 0, 1, 0, 1><<<NTILE, 1024, 0, stream>>>(
        row_ptr, col_idx, H, H, nullptr, WfB, bl1, nullptr, H1, nullptr);

    // sage2: out = [mean(H1)|H|H1] @ WfC + bl2 + bskip, stats2
    sage_k<12, 1, 0, 1, 0><<<NTILE, 1024, 0, stream>>>(
        row_ptr, col_idx, H1, H, H1, WfC, bl2, bskip, out, stats + 256);

    // BN2 + row normalize
    rownorm_k<<<(N_NODES + 3) / 4, 256, 0, stream>>>(out, stats + 256, g2, be2);
}